// Round 1
// baseline (4409.122 us; speedup 1.0000x reference)
//
#include <hip/hip_runtime.h>
#include <math.h>

#define N_GRAPHS 200000
#define NODES_PER_GRAPH 37
#define NTOT (N_GRAPHS * NODES_PER_GRAPH)   /* 7,400,000 */
#define NEDGE (8 * NTOT)                    /* 59,200,000 */

typedef int   v4i __attribute__((ext_vector_type(4)));
typedef float v4f __attribute__((ext_vector_type(4)));

// ---------------------------------------------------------------------------
// Split path, kernel 1: per-edge MLP + gather -> msg stream.
//   msg[e] = x[src[e]] * ew(edge_attr[e])
// Streaming data (src, edge_attr) loaded non-temporally so L2 keeps x lines.
// msg stored non-temporally (read exactly once by scatter_kernel).
// ---------------------------------------------------------------------------
__global__ __launch_bounds__(256) void msg_kernel(
    const float* __restrict__ x,
    const float* __restrict__ edge_attr,
    const int*   __restrict__ edge_index,   // [2, E]: src at [0,E)
    const float* __restrict__ W1, const float* __restrict__ b1,
    const float* __restrict__ W2, const float* __restrict__ b2,
    float* __restrict__ msg)
{
    const float w10 = W1[0], w11 = W1[1], w12 = W1[2], w13 = W1[3];
    const float b10 = b1[0], b11 = b1[1], b12 = b1[2], b13 = b1[3];
    const float w20 = W2[0], w21 = W2[1], w22 = W2[2], w23 = W2[3];
    const float b20 = b2[0];

    long long t  = (long long)blockIdx.x * blockDim.x + threadIdx.x;
    long long e0 = t * 4;
    if (e0 >= NEDGE) return;   // NEDGE % 4 == 0 -> full quad when in range

    v4i s  = __builtin_nontemporal_load((const v4i*)(edge_index + e0));
    v4f ea = __builtin_nontemporal_load((const v4f*)(edge_attr  + e0));

    v4f m;
    #pragma unroll
    for (int i = 0; i < 4; ++i) {
        float a  = ea[i];
        float h0 = fmaxf(fmaf(a, w10, b10), 0.f);
        float h1 = fmaxf(fmaf(a, w11, b11), 0.f);
        float h2 = fmaxf(fmaf(a, w12, b12), 0.f);
        float h3 = fmaxf(fmaf(a, w13, b13), 0.f);
        float ew = fmaf(h0, w20, fmaf(h1, w21, fmaf(h2, w22, fmaf(h3, w23, b20))));
        m[i] = x[s[i]] * ew;   // cached gather: keep x in L2
    }
    __builtin_nontemporal_store(m, (v4f*)(msg + e0));
}

// ---------------------------------------------------------------------------
// Split path, kernel 2: pure scatter.
//   atomicAdd(agg[dst[e]], msg[e])
// ---------------------------------------------------------------------------
__global__ __launch_bounds__(256) void scatter_kernel(
    const int*   __restrict__ edge_index,   // dst at [E, 2E)
    const float* __restrict__ msg,
    float* __restrict__ agg)
{
    long long t  = (long long)blockIdx.x * blockDim.x + threadIdx.x;
    long long e0 = t * 4;
    if (e0 >= NEDGE) return;

    v4i d = __builtin_nontemporal_load((const v4i*)(edge_index + (long long)NEDGE + e0));
    v4f m = __builtin_nontemporal_load((const v4f*)(msg + e0));

    atomicAdd(&agg[d[0]], m[0]);
    atomicAdd(&agg[d[1]], m[1]);
    atomicAdd(&agg[d[2]], m[2]);
    atomicAdd(&agg[d[3]], m[3]);
}

// ---------------------------------------------------------------------------
// Fallback (fused) edge kernel — used only if ws_size can't hold msg[].
// ---------------------------------------------------------------------------
__global__ __launch_bounds__(256) void edge_kernel(
    const float* __restrict__ x,
    const float* __restrict__ edge_attr,
    const int*   __restrict__ edge_index,
    const float* __restrict__ W1, const float* __restrict__ b1,
    const float* __restrict__ W2, const float* __restrict__ b2,
    float* __restrict__ agg)
{
    const float w10 = W1[0], w11 = W1[1], w12 = W1[2], w13 = W1[3];
    const float b10 = b1[0], b11 = b1[1], b12 = b1[2], b13 = b1[3];
    const float w20 = W2[0], w21 = W2[1], w22 = W2[2], w23 = W2[3];
    const float b20 = b2[0];

    long long t  = (long long)blockIdx.x * blockDim.x + threadIdx.x;
    long long e0 = t * 4;
    if (e0 >= NEDGE) return;

    int4   s  = *(const int4*)  (edge_index + e0);
    int4   d  = *(const int4*)  (edge_index + (long long)NEDGE + e0);
    float4 ea = *(const float4*)(edge_attr  + e0);

    float eav[4] = {ea.x, ea.y, ea.z, ea.w};
    int   sv[4]  = {s.x, s.y, s.z, s.w};
    int   dv[4]  = {d.x, d.y, d.z, d.w};

    float msg[4];
    #pragma unroll
    for (int i = 0; i < 4; ++i) {
        float a  = eav[i];
        float h0 = fmaxf(fmaf(a, w10, b10), 0.f);
        float h1 = fmaxf(fmaf(a, w11, b11), 0.f);
        float h2 = fmaxf(fmaf(a, w12, b12), 0.f);
        float h3 = fmaxf(fmaf(a, w13, b13), 0.f);
        float ew = fmaf(h0, w20, fmaf(h1, w21, fmaf(h2, w22, fmaf(h3, w23, b20))));
        msg[i] = x[sv[i]] * ew;
    }
    #pragma unroll
    for (int i = 0; i < 4; ++i) {
        atomicAdd(&agg[dv[i]], msg[i]);
    }
}

// ---------------------------------------------------------------------------
// Kernel 3: per-graph head (unchanged).
// ---------------------------------------------------------------------------
__global__ __launch_bounds__(256) void graph_kernel(
    const float* __restrict__ agg,
    const float* __restrict__ x,
    const float* __restrict__ rootp,
    const float* __restrict__ conv_bias,
    const float* __restrict__ Wa, const float* __restrict__ ba,
    const float* __restrict__ Wb, const float* __restrict__ bb,
    const float* __restrict__ Wc, const float* __restrict__ bc,
    float* __restrict__ out)
{
    __shared__ float s_nodes[256 * NODES_PER_GRAPH];  // 37888 B
    __shared__ float s_Wa[37 * 8];
    __shared__ float s_ba[8];
    __shared__ float s_Wb[64];
    __shared__ float s_bb[8];
    __shared__ float s_Wc[16];
    __shared__ float s_bc[2];

    const int tid = threadIdx.x;
    const float root = rootp[0];
    const float cb   = conv_bias[0];

    for (int i = tid; i < 37 * 8; i += 256) s_Wa[i] = Wa[i];
    if (tid < 64)  s_Wb[tid] = Wb[tid];
    if (tid < 16)  s_Wc[tid] = Wc[tid];
    if (tid < 8)   { s_ba[tid] = ba[tid]; s_bb[tid] = bb[tid]; }
    if (tid < 2)   s_bc[tid] = bc[tid];

    const long long base = (long long)blockIdx.x * 256 * NODES_PER_GRAPH;
    int count = 256 * NODES_PER_GRAPH;
    if (base + count > (long long)NTOT) count = (int)((long long)NTOT - base);
    for (int i = tid; i < count; i += 256) {
        long long gi = base + i;
        s_nodes[i] = fmaf(root, x[gi], agg[gi]) + cb;
    }
    __syncthreads();

    const int g = blockIdx.x * 256 + tid;
    if (g >= N_GRAPHS) return;

    const float* nd = s_nodes + tid * NODES_PER_GRAPH;

    float h1[8];
    #pragma unroll
    for (int j = 0; j < 8; ++j) h1[j] = s_ba[j];
    #pragma unroll 4
    for (int k = 0; k < NODES_PER_GRAPH; ++k) {
        float nv = nd[k];
        #pragma unroll
        for (int j = 0; j < 8; ++j) h1[j] = fmaf(nv, s_Wa[k * 8 + j], h1[j]);
    }
    #pragma unroll
    for (int j = 0; j < 8; ++j) h1[j] = fmaxf(h1[j], 0.f);

    float h2[8];
    #pragma unroll
    for (int j = 0; j < 8; ++j) {
        float acc = s_bb[j];
        #pragma unroll
        for (int k = 0; k < 8; ++k) acc = fmaf(h1[k], s_Wb[k * 8 + j], acc);
        h2[j] = fmaxf(acc, 0.f);
    }

    float X = s_bc[0], Y = s_bc[1];
    #pragma unroll
    for (int k = 0; k < 8; ++k) {
        X = fmaf(h2[k], s_Wc[k * 2 + 0], X);
        Y = fmaf(h2[k], s_Wc[k * 2 + 1], Y);
    }

    const float PI      = 3.14159265358979323846f;
    const float HALF_PI = 1.57079632679489661923f;
    float sgn   = (Y > 0.f) ? 1.f : ((Y < 0.f) ? -1.f : 0.f);
    float angle = atanf(X / Y) + HALF_PI * sgn + PI;
    out[g] = angle * (12.0f / (2.0f * PI));
}

extern "C" void kernel_launch(void* const* d_in, const int* in_sizes, int n_in,
                              void* d_out, int out_size, void* d_ws, size_t ws_size,
                              hipStream_t stream) {
    const float* x         = (const float*)d_in[0];
    const float* edge_attr = (const float*)d_in[1];
    const float* W1        = (const float*)d_in[2];
    const float* b1        = (const float*)d_in[3];
    const float* W2        = (const float*)d_in[4];
    const float* b2        = (const float*)d_in[5];
    const float* root      = (const float*)d_in[6];
    const float* conv_bias = (const float*)d_in[7];
    const float* Wa        = (const float*)d_in[8];
    const float* ba        = (const float*)d_in[9];
    const float* Wb        = (const float*)d_in[10];
    const float* bb        = (const float*)d_in[11];
    const float* Wc        = (const float*)d_in[12];
    const float* bc        = (const float*)d_in[13];
    const int*   edge_index= (const int*)d_in[14];

    float* agg = (float*)d_ws;   // NTOT floats = 29.6 MB
    hipMemsetAsync(agg, 0, (size_t)NTOT * sizeof(float), stream);

    const int threads = 256;
    const long long quads = (NEDGE + 3) / 4;
    const int blocksB = (int)((quads + threads - 1) / threads);

    const size_t need = (size_t)NTOT * sizeof(float) + (size_t)NEDGE * sizeof(float);
    if (ws_size >= need) {
        // Split/attribution path: gather-only kernel, then scatter-only kernel.
        float* msg = (float*)d_ws + NTOT;   // NEDGE floats = 236.8 MB
        msg_kernel<<<blocksB, threads, 0, stream>>>(x, edge_attr, edge_index,
                                                    W1, b1, W2, b2, msg);
        scatter_kernel<<<blocksB, threads, 0, stream>>>(edge_index, msg, agg);
    } else {
        edge_kernel<<<blocksB, threads, 0, stream>>>(x, edge_attr, edge_index,
                                                     W1, b1, W2, b2, agg);
    }

    const int blocksC = (N_GRAPHS + threads - 1) / threads;
    graph_kernel<<<blocksC, threads, 0, stream>>>(agg, x, root, conv_bias,
                                                  Wa, ba, Wb, bb, Wc, bc,
                                                  (float*)d_out);
}

// Round 2
// 2917.081 us; speedup vs baseline: 1.5115x; 1.5115x over previous
//
#include <hip/hip_runtime.h>
#include <math.h>

#define N_GRAPHS 200000
#define NODES_PER_GRAPH 37
#define NTOT (N_GRAPHS * NODES_PER_GRAPH)   /* 7,400,000 */
#define NEDGE (8 * NTOT)                    /* 59,200,000 */

// ---- dst-binning parameters -------------------------------------------------
#define BIN_SHIFT 14
#define BIN_NODES (1 << BIN_SHIFT)          /* 16384 nodes per bin (64 KB LDS) */
#define BIN_MASK  (BIN_NODES - 1)
#define NBINS 452                           /* ceil(NTOT / 16384) */
#define BIN_CAP 45000                       /* mean 43.7K + 6.4 sigma */
#define TILE 8192                           /* edges per block in binA */
#define NCHUNKS 3
#define CHUNK_E (TILE * 2409)               /* 19,734,528; 3 chunks cover NEDGE */

typedef int   v4i __attribute__((ext_vector_type(4)));
typedef float v4f __attribute__((ext_vector_type(4)));

// ---------------------------------------------------------------------------
// binA: per-tile counting-sort of edges by dst bin, fused with edge MLP +
// x[src] gather. Two passes over the tile (2nd read of dst hits L2).
//   pass 1: LDS histogram of dst>>14
//   reserve: one global atomicAdd per (tile, bin) on cursors[]
//   pass 2: msg = x[src] * ew(edge_attr); payload[bin_base+slot] = {loc, msg}
// Overflow beyond BIN_CAP (prob ~1e-10 per bin) falls back to a direct
// global atomicAdd into agg (correct, just slow for those edges).
// ---------------------------------------------------------------------------
__global__ __launch_bounds__(256) void binA_kernel(
    const float* __restrict__ x,
    const float* __restrict__ edge_attr,
    const int*   __restrict__ edge_index,   // [2, E]: src at [0,E), dst at [E,2E)
    const float* __restrict__ W1, const float* __restrict__ b1,
    const float* __restrict__ W2, const float* __restrict__ b2,
    int2* __restrict__ payload,             // [NBINS][BIN_CAP]
    int*  __restrict__ cursors,             // [NBINS]
    float* __restrict__ agg,                // overflow fallback target
    int chunk_start, int chunk_end)
{
    __shared__ int s_hist[NBINS];
    __shared__ int s_base[NBINS];
    __shared__ int s_cur[NBINS];

    const int tid = threadIdx.x;
    for (int b = tid; b < NBINS; b += 256) { s_hist[b] = 0; s_cur[b] = 0; }
    __syncthreads();

    const int tile_start = chunk_start + blockIdx.x * TILE;
    int tile_end = tile_start + TILE;
    if (tile_end > chunk_end) tile_end = chunk_end;
    // chunk bounds and TILE are multiples of 4 -> all quads are full.

    // ---- pass 1: histogram (regular loads; keeps dst tile hot in L2) ----
    for (int e0 = tile_start + tid * 4; e0 < tile_end; e0 += 256 * 4) {
        int4 d = *(const int4*)(edge_index + NEDGE + e0);
        atomicAdd(&s_hist[d.x >> BIN_SHIFT], 1);
        atomicAdd(&s_hist[d.y >> BIN_SHIFT], 1);
        atomicAdd(&s_hist[d.z >> BIN_SHIFT], 1);
        atomicAdd(&s_hist[d.w >> BIN_SHIFT], 1);
    }
    __syncthreads();

    // ---- reserve contiguous runs in the global per-bin regions ----
    for (int b = tid; b < NBINS; b += 256) {
        int c = s_hist[b];
        s_base[b] = (c > 0) ? atomicAdd(&cursors[b], c) : 0;
    }
    __syncthreads();

    // ---- pass 2: MLP + gather + binned scatter ----
    const float w10 = W1[0], w11 = W1[1], w12 = W1[2], w13 = W1[3];
    const float b10 = b1[0], b11 = b1[1], b12 = b1[2], b13 = b1[3];
    const float w20 = W2[0], w21 = W2[1], w22 = W2[2], w23 = W2[3];
    const float b20 = b2[0];

    for (int e0 = tile_start + tid * 4; e0 < tile_end; e0 += 256 * 4) {
        v4i s  = __builtin_nontemporal_load((const v4i*)(edge_index + e0));
        int4 d = *(const int4*)(edge_index + NEDGE + e0);   // L2 hit (pass 1)
        v4f ea = __builtin_nontemporal_load((const v4f*)(edge_attr + e0));

        int dv[4] = {d.x, d.y, d.z, d.w};
        #pragma unroll
        for (int i = 0; i < 4; ++i) {
            float a  = ea[i];
            float h0 = fmaxf(fmaf(a, w10, b10), 0.f);
            float h1 = fmaxf(fmaf(a, w11, b11), 0.f);
            float h2 = fmaxf(fmaf(a, w12, b12), 0.f);
            float h3 = fmaxf(fmaf(a, w13, b13), 0.f);
            float ew = fmaf(h0, w20, fmaf(h1, w21, fmaf(h2, w22, fmaf(h3, w23, b20))));
            float msg = x[s[i]] * ew;       // cached gather (L2/L3)

            int di  = dv[i];
            int bin = di >> BIN_SHIFT;
            int pos = s_base[bin] + atomicAdd(&s_cur[bin], 1);
            if (pos < BIN_CAP) {
                payload[(long long)bin * BIN_CAP + pos] =
                    make_int2(di & BIN_MASK, __float_as_int(msg));
            } else {
                atomicAdd(&agg[di], msg);   // overflow safety valve
            }
        }
    }
}

// ---------------------------------------------------------------------------
// binB: one block per bin. Accumulate the bin's payload run into a 64 KB LDS
// array with LDS atomics, then RMW the agg segment coalesced. No global
// atomics. Bin b is exclusively owned by block b; chunks are stream-ordered.
// ---------------------------------------------------------------------------
__global__ __launch_bounds__(256) void binB_kernel(
    const int2* __restrict__ payload,
    const int*  __restrict__ cursors,
    float* __restrict__ agg)
{
    __shared__ float s_agg[BIN_NODES];      // 64 KB

    const int b   = blockIdx.x;
    const int tid = threadIdx.x;

    for (int i = tid; i < BIN_NODES; i += 256) s_agg[i] = 0.f;
    __syncthreads();

    int n = cursors[b];
    if (n > BIN_CAP) n = BIN_CAP;
    const int2* p = payload + (long long)b * BIN_CAP;

    for (int i = tid; i < n; i += 256) {
        int2 v = p[i];                       // coalesced 8B
        atomicAdd(&s_agg[v.x], __int_as_float(v.y));   // ds_add_f32
    }
    __syncthreads();

    const int node0 = b << BIN_SHIFT;
    int nb = NTOT - node0;
    if (nb > BIN_NODES) nb = BIN_NODES;
    for (int i = tid; i < nb; i += 256) {
        agg[node0 + i] += s_agg[i];          // exclusive owner, no atomics
    }
}

// ---------------------------------------------------------------------------
// Fallback (fused) edge kernel — used only if ws_size is too small.
// ---------------------------------------------------------------------------
__global__ __launch_bounds__(256) void edge_kernel(
    const float* __restrict__ x,
    const float* __restrict__ edge_attr,
    const int*   __restrict__ edge_index,
    const float* __restrict__ W1, const float* __restrict__ b1,
    const float* __restrict__ W2, const float* __restrict__ b2,
    float* __restrict__ agg)
{
    const float w10 = W1[0], w11 = W1[1], w12 = W1[2], w13 = W1[3];
    const float b10 = b1[0], b11 = b1[1], b12 = b1[2], b13 = b1[3];
    const float w20 = W2[0], w21 = W2[1], w22 = W2[2], w23 = W2[3];
    const float b20 = b2[0];

    long long t  = (long long)blockIdx.x * blockDim.x + threadIdx.x;
    long long e0 = t * 4;
    if (e0 >= NEDGE) return;

    int4   s  = *(const int4*)  (edge_index + e0);
    int4   d  = *(const int4*)  (edge_index + (long long)NEDGE + e0);
    float4 ea = *(const float4*)(edge_attr  + e0);

    float eav[4] = {ea.x, ea.y, ea.z, ea.w};
    int   sv[4]  = {s.x, s.y, s.z, s.w};
    int   dv[4]  = {d.x, d.y, d.z, d.w};

    float msg[4];
    #pragma unroll
    for (int i = 0; i < 4; ++i) {
        float a  = eav[i];
        float h0 = fmaxf(fmaf(a, w10, b10), 0.f);
        float h1 = fmaxf(fmaf(a, w11, b11), 0.f);
        float h2 = fmaxf(fmaf(a, w12, b12), 0.f);
        float h3 = fmaxf(fmaf(a, w13, b13), 0.f);
        float ew = fmaf(h0, w20, fmaf(h1, w21, fmaf(h2, w22, fmaf(h3, w23, b20))));
        msg[i] = x[sv[i]] * ew;
    }
    #pragma unroll
    for (int i = 0; i < 4; ++i) {
        atomicAdd(&agg[dv[i]], msg[i]);
    }
}

// ---------------------------------------------------------------------------
// Kernel 3: per-graph head (unchanged).
// ---------------------------------------------------------------------------
__global__ __launch_bounds__(256) void graph_kernel(
    const float* __restrict__ agg,
    const float* __restrict__ x,
    const float* __restrict__ rootp,
    const float* __restrict__ conv_bias,
    const float* __restrict__ Wa, const float* __restrict__ ba,
    const float* __restrict__ Wb, const float* __restrict__ bb,
    const float* __restrict__ Wc, const float* __restrict__ bc,
    float* __restrict__ out)
{
    __shared__ float s_nodes[256 * NODES_PER_GRAPH];  // 37888 B
    __shared__ float s_Wa[37 * 8];
    __shared__ float s_ba[8];
    __shared__ float s_Wb[64];
    __shared__ float s_bb[8];
    __shared__ float s_Wc[16];
    __shared__ float s_bc[2];

    const int tid = threadIdx.x;
    const float root = rootp[0];
    const float cb   = conv_bias[0];

    for (int i = tid; i < 37 * 8; i += 256) s_Wa[i] = Wa[i];
    if (tid < 64)  s_Wb[tid] = Wb[tid];
    if (tid < 16)  s_Wc[tid] = Wc[tid];
    if (tid < 8)   { s_ba[tid] = ba[tid]; s_bb[tid] = bb[tid]; }
    if (tid < 2)   s_bc[tid] = bc[tid];

    const long long base = (long long)blockIdx.x * 256 * NODES_PER_GRAPH;
    int count = 256 * NODES_PER_GRAPH;
    if (base + count > (long long)NTOT) count = (int)((long long)NTOT - base);
    for (int i = tid; i < count; i += 256) {
        long long gi = base + i;
        s_nodes[i] = fmaf(root, x[gi], agg[gi]) + cb;
    }
    __syncthreads();

    const int g = blockIdx.x * 256 + tid;
    if (g >= N_GRAPHS) return;

    const float* nd = s_nodes + tid * NODES_PER_GRAPH;

    float h1[8];
    #pragma unroll
    for (int j = 0; j < 8; ++j) h1[j] = s_ba[j];
    #pragma unroll 4
    for (int k = 0; k < NODES_PER_GRAPH; ++k) {
        float nv = nd[k];
        #pragma unroll
        for (int j = 0; j < 8; ++j) h1[j] = fmaf(nv, s_Wa[k * 8 + j], h1[j]);
    }
    #pragma unroll
    for (int j = 0; j < 8; ++j) h1[j] = fmaxf(h1[j], 0.f);

    float h2[8];
    #pragma unroll
    for (int j = 0; j < 8; ++j) {
        float acc = s_bb[j];
        #pragma unroll
        for (int k = 0; k < 8; ++k) acc = fmaf(h1[k], s_Wb[k * 8 + j], acc);
        h2[j] = fmaxf(acc, 0.f);
    }

    float X = s_bc[0], Y = s_bc[1];
    #pragma unroll
    for (int k = 0; k < 8; ++k) {
        X = fmaf(h2[k], s_Wc[k * 2 + 0], X);
        Y = fmaf(h2[k], s_Wc[k * 2 + 1], Y);
    }

    const float PI      = 3.14159265358979323846f;
    const float HALF_PI = 1.57079632679489661923f;
    float sgn   = (Y > 0.f) ? 1.f : ((Y < 0.f) ? -1.f : 0.f);
    float angle = atanf(X / Y) + HALF_PI * sgn + PI;
    out[g] = angle * (12.0f / (2.0f * PI));
}

extern "C" void kernel_launch(void* const* d_in, const int* in_sizes, int n_in,
                              void* d_out, int out_size, void* d_ws, size_t ws_size,
                              hipStream_t stream) {
    const float* x         = (const float*)d_in[0];
    const float* edge_attr = (const float*)d_in[1];
    const float* W1        = (const float*)d_in[2];
    const float* b1        = (const float*)d_in[3];
    const float* W2        = (const float*)d_in[4];
    const float* b2        = (const float*)d_in[5];
    const float* root      = (const float*)d_in[6];
    const float* conv_bias = (const float*)d_in[7];
    const float* Wa        = (const float*)d_in[8];
    const float* ba        = (const float*)d_in[9];
    const float* Wb        = (const float*)d_in[10];
    const float* bb        = (const float*)d_in[11];
    const float* Wc        = (const float*)d_in[12];
    const float* bc        = (const float*)d_in[13];
    const int*   edge_index= (const int*)d_in[14];

    const int threads = 256;

    // workspace layout: agg | payload | cursors
    float* agg = (float*)d_ws;                                   // 29.6 MB
    size_t offPayload = (size_t)NTOT * sizeof(float);
    int2*  payload = (int2*)((char*)d_ws + offPayload);          // 162.7 MB
    size_t offCursors = offPayload + (size_t)NBINS * BIN_CAP * sizeof(int2);
    int*   cursors = (int*)((char*)d_ws + offCursors);
    size_t need = offCursors + (size_t)NBINS * sizeof(int);      // ~192.3 MB

    hipMemsetAsync(agg, 0, (size_t)NTOT * sizeof(float), stream);

    if (ws_size >= need) {
        for (int c = 0; c < NCHUNKS; ++c) {
            int cs = c * CHUNK_E;
            int ce = cs + CHUNK_E;
            if (ce > NEDGE) ce = NEDGE;
            hipMemsetAsync(cursors, 0, (size_t)NBINS * sizeof(int), stream);
            int tiles = (ce - cs + TILE - 1) / TILE;
            binA_kernel<<<tiles, threads, 0, stream>>>(
                x, edge_attr, edge_index, W1, b1, W2, b2,
                payload, cursors, agg, cs, ce);
            binB_kernel<<<NBINS, threads, 0, stream>>>(payload, cursors, agg);
        }
    } else {
        // Fallback: fused atomic scatter.
        const long long quads = (NEDGE + 3) / 4;
        const int blocksB = (int)((quads + threads - 1) / threads);
        edge_kernel<<<blocksB, threads, 0, stream>>>(x, edge_attr, edge_index,
                                                     W1, b1, W2, b2, agg);
    }

    const int blocksC = (N_GRAPHS + threads - 1) / threads;
    graph_kernel<<<blocksC, threads, 0, stream>>>(agg, x, root, conv_bias,
                                                  Wa, ba, Wb, bb, Wc, bc,
                                                  (float*)d_out);
}

// Round 3
// 2144.171 us; speedup vs baseline: 2.0563x; 1.3605x over previous
//
#include <hip/hip_runtime.h>
#include <math.h>

#define N_GRAPHS 200000
#define NODES_PER_GRAPH 37
#define NTOT (N_GRAPHS * NODES_PER_GRAPH)   /* 7,400,000 */
#define NEDGE (8 * NTOT)                    /* 59,200,000 */

// ---- dst-binning parameters -------------------------------------------------
#define BIN_SHIFT 14
#define BIN_NODES (1 << BIN_SHIFT)          /* 16384 nodes per bin (64 KB LDS) */
#define BIN_MASK  (BIN_NODES - 1)
#define NBINS 452                           /* ceil(NTOT / 16384) */

#define TILE 8192                           /* edges per binA block */
#define THREADS_A 512
#define QUADS_PT 4                          /* TILE / (THREADS_A*4) */

#define CAP3 45000                          /* 3-chunk tier: mean 43.7K + 6.4σ */
#define CHUNK_E (TILE * 2409)               /* 19,734,528; 3 chunks cover NEDGE */
#define CAP1 136000                         /* 1-chunk tier: mean 131K + ~14σ */

typedef int   v4i __attribute__((ext_vector_type(4)));
typedef float v4f __attribute__((ext_vector_type(4)));
typedef int   v2i __attribute__((ext_vector_type(2)));

// ---------------------------------------------------------------------------
// binA: per-tile counting sort of edges by dst bin (in LDS), fused with the
// edge MLP + x[src] gather. Output payload writes are COALESCED:
//   phase 1: load dst quads (kept in VGPRs) + LDS histogram of dst>>14
//   scan   : block prefix-sum over 452 bins; reserve global runs (1 atomic/bin)
//   phase 2: msg = x[src]*ew; scatter {dst, msg} to LDS staging at sorted pos
//   phase 3: linear flush — lane i writes staging[i] to its bin's global run
// Overflow past cap falls back to a direct global atomicAdd (prob ~0).
// ---------------------------------------------------------------------------
__global__ __launch_bounds__(THREADS_A) void binA_kernel(
    const float* __restrict__ x,
    const float* __restrict__ edge_attr,
    const int*   __restrict__ edge_index,   // [2, E]: src at [0,E), dst at [E,2E)
    const float* __restrict__ W1, const float* __restrict__ b1,
    const float* __restrict__ W2, const float* __restrict__ b2,
    int2* __restrict__ payload,             // [NBINS][cap]
    int*  __restrict__ cursors,             // [NBINS]
    float* __restrict__ agg,                // overflow fallback target
    int cap, int chunk_start, int chunk_end)
{
    __shared__ int2 s_stage[TILE];          // 64 KB
    __shared__ int  s_hist[NBINS];
    __shared__ int  s_lstart[NBINS];
    __shared__ int  s_gbase[NBINS];
    __shared__ int  s_cur[NBINS];
    __shared__ int  s_scan[THREADS_A];

    const int tid = threadIdx.x;
    for (int b = tid; b < NBINS; b += THREADS_A) { s_hist[b] = 0; s_cur[b] = 0; }
    __syncthreads();

    const int tile_start = chunk_start + blockIdx.x * TILE;
    int tile_end = tile_start + TILE;
    if (tile_end > chunk_end) tile_end = chunk_end;
    const int count = tile_end - tile_start;   // multiple of 4

    // ---- phase 1: dst loads (kept in regs) + histogram ----
    int4 dq[QUADS_PT];
    #pragma unroll
    for (int j = 0; j < QUADS_PT; ++j) {
        int e0 = tile_start + (tid + j * THREADS_A) * 4;
        if (e0 < tile_end) {
            v4i d = __builtin_nontemporal_load(
                        (const v4i*)(edge_index + (long long)NEDGE + e0));
            dq[j] = make_int4(d[0], d[1], d[2], d[3]);
            atomicAdd(&s_hist[d[0] >> BIN_SHIFT], 1);
            atomicAdd(&s_hist[d[1] >> BIN_SHIFT], 1);
            atomicAdd(&s_hist[d[2] >> BIN_SHIFT], 1);
            atomicAdd(&s_hist[d[3] >> BIN_SHIFT], 1);
        } else {
            dq[j] = make_int4(0, 0, 0, 0);
        }
    }
    __syncthreads();

    // ---- block prefix scan (Hillis-Steele over 512 slots) ----
    int v = (tid < NBINS) ? s_hist[tid] : 0;
    s_scan[tid] = v;
    __syncthreads();
    for (int off = 1; off < THREADS_A; off <<= 1) {
        int t = (tid >= off) ? s_scan[tid - off] : 0;
        __syncthreads();
        s_scan[tid] += t;
        __syncthreads();
    }
    if (tid < NBINS) {
        s_lstart[tid] = s_scan[tid] - v;   // exclusive prefix
        s_gbase[tid]  = (v > 0) ? atomicAdd(&cursors[tid], v) : 0;
    }
    __syncthreads();

    // ---- phase 2: MLP + gather + sorted LDS scatter ----
    const float w10 = W1[0], w11 = W1[1], w12 = W1[2], w13 = W1[3];
    const float b10 = b1[0], b11 = b1[1], b12 = b1[2], b13 = b1[3];
    const float w20 = W2[0], w21 = W2[1], w22 = W2[2], w23 = W2[3];
    const float b20 = b2[0];

    #pragma unroll
    for (int j = 0; j < QUADS_PT; ++j) {
        int e0 = tile_start + (tid + j * THREADS_A) * 4;
        if (e0 < tile_end) {
            v4i s  = __builtin_nontemporal_load((const v4i*)(edge_index + e0));
            v4f ea = __builtin_nontemporal_load((const v4f*)(edge_attr + e0));
            int dv[4] = {dq[j].x, dq[j].y, dq[j].z, dq[j].w};
            #pragma unroll
            for (int i = 0; i < 4; ++i) {
                float a  = ea[i];
                float h0 = fmaxf(fmaf(a, w10, b10), 0.f);
                float h1 = fmaxf(fmaf(a, w11, b11), 0.f);
                float h2 = fmaxf(fmaf(a, w12, b12), 0.f);
                float h3 = fmaxf(fmaf(a, w13, b13), 0.f);
                float ew = fmaf(h0, w20, fmaf(h1, w21, fmaf(h2, w22, fmaf(h3, w23, b20))));
                float msg = x[s[i]] * ew;           // cached gather (L2/L3)

                int di  = dv[i];
                int bin = di >> BIN_SHIFT;
                int pos = s_lstart[bin] + atomicAdd(&s_cur[bin], 1);
                s_stage[pos] = make_int2(di, __float_as_int(msg));
            }
        }
    }
    __syncthreads();

    // ---- phase 3: coalesced flush ----
    #pragma unroll
    for (int j = 0; j < QUADS_PT * 4; ++j) {
        int i = tid + j * THREADS_A;
        if (i < count) {
            int2 e  = s_stage[i];
            int di  = e.x;
            int bin = di >> BIN_SHIFT;
            int gp  = s_gbase[bin] + (i - s_lstart[bin]);
            if (gp < cap) {
                v2i out; out[0] = di & BIN_MASK; out[1] = e.y;
                __builtin_nontemporal_store(out,
                    (v2i*)(payload + (long long)bin * cap + gp));
            } else {
                atomicAdd(&agg[di], __int_as_float(e.y));   // overflow valve
            }
        }
    }
}

// ---------------------------------------------------------------------------
// binB: one block per bin. Accumulate the bin's payload into 64 KB LDS with
// LDS atomics, then RMW the agg segment coalesced. No global atomics.
// ---------------------------------------------------------------------------
__global__ __launch_bounds__(512) void binB_kernel(
    const int2* __restrict__ payload,
    const int*  __restrict__ cursors,
    float* __restrict__ agg, int cap)
{
    __shared__ float s_agg[BIN_NODES];      // 64 KB

    const int b   = blockIdx.x;
    const int tid = threadIdx.x;

    for (int i = tid; i < BIN_NODES; i += 512) s_agg[i] = 0.f;
    __syncthreads();

    int n = cursors[b];
    if (n > cap) n = cap;
    const int2* p = payload + (long long)b * cap;

    for (int i = tid; i < n; i += 512) {
        int2 e = p[i];                        // coalesced 8B
        atomicAdd(&s_agg[e.x & BIN_MASK], __int_as_float(e.y));   // ds_add_f32
    }
    __syncthreads();

    const int node0 = b << BIN_SHIFT;
    int nb = NTOT - node0;
    if (nb > BIN_NODES) nb = BIN_NODES;
    for (int i = tid; i < nb; i += 512) {
        agg[node0 + i] += s_agg[i];           // exclusive owner, no atomics
    }
}

// ---------------------------------------------------------------------------
// Fallback (fused) edge kernel — used only if ws_size is too small.
// ---------------------------------------------------------------------------
__global__ __launch_bounds__(256) void edge_kernel(
    const float* __restrict__ x,
    const float* __restrict__ edge_attr,
    const int*   __restrict__ edge_index,
    const float* __restrict__ W1, const float* __restrict__ b1,
    const float* __restrict__ W2, const float* __restrict__ b2,
    float* __restrict__ agg)
{
    const float w10 = W1[0], w11 = W1[1], w12 = W1[2], w13 = W1[3];
    const float b10 = b1[0], b11 = b1[1], b12 = b1[2], b13 = b1[3];
    const float w20 = W2[0], w21 = W2[1], w22 = W2[2], w23 = W2[3];
    const float b20 = b2[0];

    long long t  = (long long)blockIdx.x * blockDim.x + threadIdx.x;
    long long e0 = t * 4;
    if (e0 >= NEDGE) return;

    int4   s  = *(const int4*)  (edge_index + e0);
    int4   d  = *(const int4*)  (edge_index + (long long)NEDGE + e0);
    float4 ea = *(const float4*)(edge_attr  + e0);

    float eav[4] = {ea.x, ea.y, ea.z, ea.w};
    int   sv[4]  = {s.x, s.y, s.z, s.w};
    int   dv[4]  = {d.x, d.y, d.z, d.w};

    float msg[4];
    #pragma unroll
    for (int i = 0; i < 4; ++i) {
        float a  = eav[i];
        float h0 = fmaxf(fmaf(a, w10, b10), 0.f);
        float h1 = fmaxf(fmaf(a, w11, b11), 0.f);
        float h2 = fmaxf(fmaf(a, w12, b12), 0.f);
        float h3 = fmaxf(fmaf(a, w13, b13), 0.f);
        float ew = fmaf(h0, w20, fmaf(h1, w21, fmaf(h2, w22, fmaf(h3, w23, b20))));
        msg[i] = x[sv[i]] * ew;
    }
    #pragma unroll
    for (int i = 0; i < 4; ++i) {
        atomicAdd(&agg[dv[i]], msg[i]);
    }
}

// ---------------------------------------------------------------------------
// Kernel 3: per-graph head (unchanged).
// ---------------------------------------------------------------------------
__global__ __launch_bounds__(256) void graph_kernel(
    const float* __restrict__ agg,
    const float* __restrict__ x,
    const float* __restrict__ rootp,
    const float* __restrict__ conv_bias,
    const float* __restrict__ Wa, const float* __restrict__ ba,
    const float* __restrict__ Wb, const float* __restrict__ bb,
    const float* __restrict__ Wc, const float* __restrict__ bc,
    float* __restrict__ out)
{
    __shared__ float s_nodes[256 * NODES_PER_GRAPH];  // 37888 B
    __shared__ float s_Wa[37 * 8];
    __shared__ float s_ba[8];
    __shared__ float s_Wb[64];
    __shared__ float s_bb[8];
    __shared__ float s_Wc[16];
    __shared__ float s_bc[2];

    const int tid = threadIdx.x;
    const float root = rootp[0];
    const float cb   = conv_bias[0];

    for (int i = tid; i < 37 * 8; i += 256) s_Wa[i] = Wa[i];
    if (tid < 64)  s_Wb[tid] = Wb[tid];
    if (tid < 16)  s_Wc[tid] = Wc[tid];
    if (tid < 8)   { s_ba[tid] = ba[tid]; s_bb[tid] = bb[tid]; }
    if (tid < 2)   s_bc[tid] = bc[tid];

    const long long base = (long long)blockIdx.x * 256 * NODES_PER_GRAPH;
    int count = 256 * NODES_PER_GRAPH;
    if (base + count > (long long)NTOT) count = (int)((long long)NTOT - base);
    for (int i = tid; i < count; i += 256) {
        long long gi = base + i;
        s_nodes[i] = fmaf(root, x[gi], agg[gi]) + cb;
    }
    __syncthreads();

    const int g = blockIdx.x * 256 + tid;
    if (g >= N_GRAPHS) return;

    const float* nd = s_nodes + tid * NODES_PER_GRAPH;

    float h1[8];
    #pragma unroll
    for (int j = 0; j < 8; ++j) h1[j] = s_ba[j];
    #pragma unroll 4
    for (int k = 0; k < NODES_PER_GRAPH; ++k) {
        float nv = nd[k];
        #pragma unroll
        for (int j = 0; j < 8; ++j) h1[j] = fmaf(nv, s_Wa[k * 8 + j], h1[j]);
    }
    #pragma unroll
    for (int j = 0; j < 8; ++j) h1[j] = fmaxf(h1[j], 0.f);

    float h2[8];
    #pragma unroll
    for (int j = 0; j < 8; ++j) {
        float acc = s_bb[j];
        #pragma unroll
        for (int k = 0; k < 8; ++k) acc = fmaf(h1[k], s_Wb[k * 8 + j], acc);
        h2[j] = fmaxf(acc, 0.f);
    }

    float X = s_bc[0], Y = s_bc[1];
    #pragma unroll
    for (int k = 0; k < 8; ++k) {
        X = fmaf(h2[k], s_Wc[k * 2 + 0], X);
        Y = fmaf(h2[k], s_Wc[k * 2 + 1], Y);
    }

    const float PI      = 3.14159265358979323846f;
    const float HALF_PI = 1.57079632679489661923f;
    float sgn   = (Y > 0.f) ? 1.f : ((Y < 0.f) ? -1.f : 0.f);
    float angle = atanf(X / Y) + HALF_PI * sgn + PI;
    out[g] = angle * (12.0f / (2.0f * PI));
}

extern "C" void kernel_launch(void* const* d_in, const int* in_sizes, int n_in,
                              void* d_out, int out_size, void* d_ws, size_t ws_size,
                              hipStream_t stream) {
    const float* x         = (const float*)d_in[0];
    const float* edge_attr = (const float*)d_in[1];
    const float* W1        = (const float*)d_in[2];
    const float* b1        = (const float*)d_in[3];
    const float* W2        = (const float*)d_in[4];
    const float* b2        = (const float*)d_in[5];
    const float* root      = (const float*)d_in[6];
    const float* conv_bias = (const float*)d_in[7];
    const float* Wa        = (const float*)d_in[8];
    const float* ba        = (const float*)d_in[9];
    const float* Wb        = (const float*)d_in[10];
    const float* bb        = (const float*)d_in[11];
    const float* Wc        = (const float*)d_in[12];
    const float* bc        = (const float*)d_in[13];
    const int*   edge_index= (const int*)d_in[14];

    float* agg = (float*)d_ws;                       // 29.6 MB
    size_t offPayload = (size_t)NTOT * sizeof(float);

    const size_t need1 = offPayload + (size_t)NBINS * CAP1 * sizeof(int2)
                       + (size_t)NBINS * sizeof(int);                 /* ~522 MB */
    const size_t need3 = offPayload + (size_t)NBINS * CAP3 * sizeof(int2)
                       + (size_t)NBINS * sizeof(int);                 /* ~192 MB */

    hipMemsetAsync(agg, 0, (size_t)NTOT * sizeof(float), stream);

    if (ws_size >= need1) {
        // --- 1-chunk tier ---
        int2* payload = (int2*)((char*)d_ws + offPayload);
        int*  cursors = (int*)((char*)d_ws + offPayload
                               + (size_t)NBINS * CAP1 * sizeof(int2));
        hipMemsetAsync(cursors, 0, (size_t)NBINS * sizeof(int), stream);
        int tiles = (NEDGE + TILE - 1) / TILE;       // 7227
        binA_kernel<<<tiles, THREADS_A, 0, stream>>>(
            x, edge_attr, edge_index, W1, b1, W2, b2,
            payload, cursors, agg, CAP1, 0, NEDGE);
        binB_kernel<<<NBINS, 512, 0, stream>>>(payload, cursors, agg, CAP1);
    } else if (ws_size >= need3) {
        // --- 3-chunk tier ---
        int2* payload = (int2*)((char*)d_ws + offPayload);
        int*  cursors = (int*)((char*)d_ws + offPayload
                               + (size_t)NBINS * CAP3 * sizeof(int2));
        for (int c = 0; c < 3; ++c) {
            int cs = c * CHUNK_E;
            int ce = cs + CHUNK_E;
            if (ce > NEDGE) ce = NEDGE;
            hipMemsetAsync(cursors, 0, (size_t)NBINS * sizeof(int), stream);
            int tiles = (ce - cs + TILE - 1) / TILE;
            binA_kernel<<<tiles, THREADS_A, 0, stream>>>(
                x, edge_attr, edge_index, W1, b1, W2, b2,
                payload, cursors, agg, CAP3, cs, ce);
            binB_kernel<<<NBINS, 512, 0, stream>>>(payload, cursors, agg, CAP3);
        }
    } else {
        // --- fused fallback ---
        const long long quads = (NEDGE + 3) / 4;
        const int blocksB = (int)((quads + 255) / 256);
        edge_kernel<<<blocksB, 256, 0, stream>>>(x, edge_attr, edge_index,
                                                 W1, b1, W2, b2, agg);
    }

    const int blocksC = (N_GRAPHS + 255) / 256;
    graph_kernel<<<blocksC, 256, 0, stream>>>(agg, x, root, conv_bias,
                                              Wa, ba, Wb, bb, Wc, bc,
                                              (float*)d_out);
}